// Round 4
// baseline (302.821 us; speedup 1.0000x reference)
//
#include <hip/hip_runtime.h>

// MAUCHLoss: B=2097152 rows, C=15 categories, f32 inputs.
//
// R11: R8/R9/R10 post-mortem — all three regressions share VGPR_Count=32,
// and all three used __launch_bounds__(256,8). On this toolchain the
// min-waves=8 arg maps to a 32-VGPR cap (not 64), which spills the
// ACCUMULATORS (serial dependency chain) -> every iteration stalls on
// scratch regardless of occupancy. Rule: never pass a min-waves arg.
// R7 (112 VGPR, 15 waves/CU, 55us) ran at its allowed occupancy; the
// still-untested lever is 32 waves/CU, which needs VGPR<=64 BY
// CONSTRUCTION: PF=2 register ring (16 data regs + 13 accum + ~10 addr
// ~= 50 VGPR), #pragma unroll 2 with peeled tail so ring indices are
// compile-time while the back-edge every 2 iters limits scheduler
// hoisting (the pressure balloon under full unroll). Latency hiding via
// TLP: 32 waves/CU x 4KB in flight = 128KB/CU >> ~9KB needed.
// Keep: 1920 blocks (=15*2^7 -> per-thread category phase constant),
// plain loads (L2/L3 hits are real per FETCH), per-block partial
// stores (no global atomics, no ws memset dispatch).
//
// ws layout (mode=1): ws[k*PLD + block], k in [0,46): 0..14 sum(sig),
// 15..29 sum(sig*label), 30..44 sum(label), 45 sum(softplus(-sig)).

#define CATS 15
#define NBLOCKS 1920  // 1920*256*4 = 1,966,080 = 15*131072 -> phase constant
#define NTHREADS 256
#define NSUMS (3 * CATS + 1)   // 46
#define ITERS 16               // nFloat4 / stride for the fixed problem size
#define PF 2                   // ring depth: 16 data VGPRs
#define PLD 2048               // partials stride in floats (>= NBLOCKS)

typedef float vf4 __attribute__((ext_vector_type(4)));

// softplus(-s) = log(1+exp(-s)) on s in (0,1): degree-4 poly, |err| < 1e-4.
__device__ __forceinline__ float softplus_neg_unit(float s) {
    const float c0 = 0.69314718f, c1 = -0.5f, c2 = 0.125f, c4 = -0.0048853f;
    float s2 = s * s;
    return c0 + fmaf(c1, s, fmaf(c2, s2, c4 * s2 * s2));
}

__device__ __forceinline__ void accum_elem(float x, float l,
                                           float& ssig, float& spos, float& snp,
                                           float& scel) {
    float e   = __expf(-x);                       // transcendental 1
    float sig = __builtin_amdgcn_rcpf(1.0f + e);  // transcendental 2
    ssig += sig;
    spos = fmaf(sig, l, spos);
    snp  += l;
    scel += softplus_neg_unit(sig);
}

__global__ __launch_bounds__(NTHREADS) void mauch_main(
    const float* __restrict__ outp, const float* __restrict__ labp,
    float* __restrict__ ws, int nFloat4, int mode)
{
    const int t = blockIdx.x * blockDim.x + threadIdx.x;
    const int stride = gridDim.x * blockDim.x;   // stride*4 % 15 == 0

    float ssig[4] = {0.f, 0.f, 0.f, 0.f};
    float spos[4] = {0.f, 0.f, 0.f, 0.f};
    float snp[4]  = {0.f, 0.f, 0.f, 0.f};
    float scel = 0.f;

    const vf4* o4 = (const vf4*)outp;
    const vf4* l4 = (const vf4*)labp;

    if (nFloat4 == ITERS * stride) {
        // fixed-size fast path: PF=2 register ring.
        vf4 ob[PF], lb[PF];
#pragma unroll
        for (int p = 0; p < PF; ++p) {
            ob[p] = o4[t + p * stride];
            lb[p] = l4[t + p * stride];
        }
        // steady state: consume slot, refill slot for i+PF.
        // unroll 2 => i&1 is compile-time per body (regs, no scratch),
        // back-edge every 2 iters bounds the scheduler's hoist window.
#pragma unroll 2
        for (int i = 0; i < ITERS - PF; ++i) {
            vf4 ov = ob[i & 1];
            vf4 lv = lb[i & 1];
            ob[i & 1] = o4[t + (i + PF) * stride];
            lb[i & 1] = l4[t + (i + PF) * stride];
#pragma unroll
            for (int j = 0; j < 4; ++j)
                accum_elem(ov[j], lv[j], ssig[j], spos[j], snp[j], scel);
        }
        // peeled tail: drain the ring, no refill.
#pragma unroll
        for (int i = ITERS - PF; i < ITERS; ++i) {
            vf4 ov = ob[i & 1];
            vf4 lv = lb[i & 1];
#pragma unroll
            for (int j = 0; j < 4; ++j)
                accum_elem(ov[j], lv[j], ssig[j], spos[j], snp[j], scel);
        }
    } else {
#pragma unroll 1
        for (int f = t; f < nFloat4; f += stride) {
            vf4 ov = o4[f];
            vf4 lv = l4[f];
#pragma unroll
            for (int j = 0; j < 4; ++j)
                accum_elem(ov[j], lv[j], ssig[j], spos[j], snp[j], scel);
        }
    }

    // ---- block reduction in LDS ----
    __shared__ float red[NSUMS];
    for (int i = threadIdx.x; i < NSUMS; i += blockDim.x) red[i] = 0.f;
    __syncthreads();

    // element categories for this thread: (4t + j) mod 15, constant across iterations
    int base = (4 * t) % CATS;
#pragma unroll
    for (int j = 0; j < 4; ++j) {
        int c = base + j; if (c >= CATS) c -= CATS;
        atomicAdd(&red[c],            ssig[j]);
        atomicAdd(&red[CATS + c],     spos[j]);
        atomicAdd(&red[2 * CATS + c], snp[j]);
    }
    atomicAdd(&red[3 * CATS], scel);
    __syncthreads();

    if (threadIdx.x < NSUMS) {
        if (mode) ws[threadIdx.x * PLD + blockIdx.x] = red[threadIdx.x];  // no atomics, poison-safe
        else      atomicAdd(&ws[threadIdx.x], red[threadIdx.x]);          // small-ws fallback
    }
}

__global__ __launch_bounds__(1024) void mauch_final(
    const float* __restrict__ ws, float* __restrict__ out,
    float invBC, float rowsB, int mode)
{
    __shared__ float sums[NSUMS];
    const int lane = threadIdx.x & 63;
    const int wv   = threadIdx.x >> 6;   // 16 waves

    if (mode) {
        // one wave per sum slot: coalesced strided read + shuffle reduce
        for (int k = wv; k < NSUMS; k += 16) {
            float v = 0.f;
            for (int b = lane; b < NBLOCKS; b += 64) v += ws[k * PLD + b];
#pragma unroll
            for (int off = 32; off; off >>= 1) v += __shfl_down(v, off, 64);
            if (lane == 0) sums[k] = v;
        }
    } else {
        if (threadIdx.x < NSUMS) sums[threadIdx.x] = ws[threadIdx.x];
    }
    __syncthreads();

    if (threadIdx.x == 0) {
        float sum_term = 0.f, pen_last = 0.f;
        float tot_ssig = 0.f, tot_spos = 0.f;
#pragma unroll
        for (int c = 0; c < CATS; ++c) {
            float ssigc = sums[c];
            float sp    = sums[CATS + c];
            float np    = sums[2 * CATS + c];
            float nn    = rowsB - np;
            float sneg  = ssigc - sp;
            tot_ssig += ssigc;
            tot_spos += sp;
            float mp = (np > 0.f) ? sp   / fmaxf(np, 1.f) : 0.f;
            float mn = (nn > 0.f) ? sneg / fmaxf(nn, 1.f) : 0.f;
            float pen = 1.f - mp + mn;
            sum_term += pen;
            if (c == CATS - 1) pen_last = pen;
        }
        // cel = mean(sp + (1-l)*sig); sum((1-l)*sig) = sum(sig) - sum(sig*l)
        float cel = (sums[3 * CATS] + (tot_ssig - tot_spos)) * invBC;
        out[0] = cel + 0.1f * (sum_term / 15.f);
        out[1] = 0.1f * pen_last;
    }
}

extern "C" void kernel_launch(void* const* d_in, const int* in_sizes, int n_in,
                              void* d_out, int out_size, void* d_ws, size_t ws_size,
                              hipStream_t stream) {
    const float* outp = (const float*)d_in[0];
    const float* labp = (const float*)d_in[1];
    float* out = (float*)d_out;
    float* ws  = (float*)d_ws;

    const int total   = in_sizes[0];          // B * 15
    const int nFloat4 = total / 4;
    const float rowsB = (float)(total / CATS);
    const float invBC = 1.0f / (float)total;

    const size_t needed = (size_t)NSUMS * PLD * sizeof(float);
    const int mode = (ws_size >= needed) ? 1 : 0;
    if (!mode) hipMemsetAsync(ws, 0, NSUMS * sizeof(float), stream);  // only for atomic fallback

    mauch_main<<<NBLOCKS, NTHREADS, 0, stream>>>(outp, labp, ws, nFloat4, mode);
    mauch_final<<<1, 1024, 0, stream>>>(ws, out, invBC, rowsB, mode);
}

// Round 5
// 263.870 us; speedup vs baseline: 1.1476x; 1.1476x over previous
//
#include <hip/hip_runtime.h>

// MAUCHLoss: B=2097152 rows, C=15 categories, f32 inputs.
//
// R12: recovery to the known-good anchor. R8-R11 post-mortem:
// VGPR_Count=32 reported for four different kernels incl. R11 with no
// min-waves bound -> the launch-bounds/spill theory is dead (R11 had no
// spill: WRITE 2.9MB) yet still 111us at 2.27 TB/s effective. Implied
// in-flight per CU ~3KB (Little's law) -> per-CU load concurrency is
// being serialized in the cache path. The one variable every slow round
// (R8-R11, 1.2-2.3 TB/s) shares vs the fast anchor R7 (4.6 TB/s):
// plain cached loads vs __builtin_nontemporal_load. NT bypasses L1
// allocation (streaming data has zero reuse) and its miss-tracking
// serialization. So: restore R7's main exactly (NT, PF=8 ring,
// ITERS=32, 960 blocks, no min-waves bound), keep only the epilogue
// improvements (per-block partial stores, no memset dispatch, parallel
// final reduce). Expected main ~55us. Next single-variable probe from
// this anchor: NT + PF=3 (~45 VGPR -> 8 waves/SIMD by construction).
//
// ws layout (mode=1): ws[k*PLD + block], k in [0,46): 0..14 sum(sig),
// 15..29 sum(sig*label), 30..44 sum(label), 45 sum(softplus(-sig)).

#define CATS 15
#define NBLOCKS 960   // 960*256*4 = 983,040 = 15*65536 -> category phase constant
#define NTHREADS 256
#define NSUMS (3 * CATS + 1)   // 46
#define PF 8                   // pipeline depth (iterations ahead) — R7 anchor
#define ITERS 32               // nFloat4 / stride for the fixed problem size
#define PLD 2048               // partials stride in floats (>= NBLOCKS)

typedef float vf4 __attribute__((ext_vector_type(4)));

__device__ __forceinline__ vf4 ntload4(const vf4* p) {
    return __builtin_nontemporal_load(p);
}

// softplus(-s) = log(1+exp(-s)) on s in (0,1): degree-4 poly, |err| < 1e-4.
__device__ __forceinline__ float softplus_neg_unit(float s) {
    const float c0 = 0.69314718f, c1 = -0.5f, c2 = 0.125f, c4 = -0.0048853f;
    float s2 = s * s;
    return c0 + fmaf(c1, s, fmaf(c2, s2, c4 * s2 * s2));
}

__device__ __forceinline__ void accum_elem(float x, float l,
                                           float& ssig, float& spos, float& snp,
                                           float& scel) {
    float e   = __expf(-x);                       // transcendental 1
    float sig = __builtin_amdgcn_rcpf(1.0f + e);  // transcendental 2
    ssig += sig;
    spos = fmaf(sig, l, spos);
    snp  += l;
    scel += softplus_neg_unit(sig);
}

__global__ __launch_bounds__(NTHREADS) void mauch_main(
    const float* __restrict__ outp, const float* __restrict__ labp,
    float* __restrict__ ws, int nFloat4, int mode)
{
    const int t = blockIdx.x * blockDim.x + threadIdx.x;
    const int stride = gridDim.x * blockDim.x;   // stride*4 % 15 == 0

    float ssig[4] = {0.f, 0.f, 0.f, 0.f};
    float spos[4] = {0.f, 0.f, 0.f, 0.f};
    float snp[4]  = {0.f, 0.f, 0.f, 0.f};
    float scel = 0.f;

    const vf4* o4 = (const vf4*)outp;
    const vf4* l4 = (const vf4*)labp;

    if (nFloat4 == ITERS * stride) {
        // fixed-size fast path: explicit PF-deep register pipeline (R7 anchor)
        vf4 ob[PF], lb[PF];
#pragma unroll
        for (int p = 0; p < PF; ++p) {
            ob[p] = ntload4(o4 + t + p * stride);
            lb[p] = ntload4(l4 + t + p * stride);
        }
#pragma unroll
        for (int i = 0; i < ITERS; ++i) {
            vf4 ov = ob[i % PF];
            vf4 lv = lb[i % PF];
            if (i + PF < ITERS) {
                ob[i % PF] = ntload4(o4 + t + (i + PF) * stride);
                lb[i % PF] = ntload4(l4 + t + (i + PF) * stride);
            }
#pragma unroll
            for (int j = 0; j < 4; ++j)
                accum_elem(ov[j], lv[j], ssig[j], spos[j], snp[j], scel);
        }
    } else {
#pragma unroll 1
        for (int f = t; f < nFloat4; f += stride) {
            vf4 ov = ntload4(o4 + f);
            vf4 lv = ntload4(l4 + f);
#pragma unroll
            for (int j = 0; j < 4; ++j)
                accum_elem(ov[j], lv[j], ssig[j], spos[j], snp[j], scel);
        }
    }

    // ---- block reduction in LDS ----
    __shared__ float red[NSUMS];
    for (int i = threadIdx.x; i < NSUMS; i += blockDim.x) red[i] = 0.f;
    __syncthreads();

    // element categories for this thread: (4t + j) mod 15, constant across iterations
    int base = (4 * t) % CATS;
#pragma unroll
    for (int j = 0; j < 4; ++j) {
        int c = base + j; if (c >= CATS) c -= CATS;
        atomicAdd(&red[c],            ssig[j]);
        atomicAdd(&red[CATS + c],     spos[j]);
        atomicAdd(&red[2 * CATS + c], snp[j]);
    }
    atomicAdd(&red[3 * CATS], scel);
    __syncthreads();

    if (threadIdx.x < NSUMS) {
        if (mode) ws[threadIdx.x * PLD + blockIdx.x] = red[threadIdx.x];  // no atomics, poison-safe
        else      atomicAdd(&ws[threadIdx.x], red[threadIdx.x]);          // small-ws fallback
    }
}

__global__ __launch_bounds__(1024) void mauch_final(
    const float* __restrict__ ws, float* __restrict__ out,
    float invBC, float rowsB, int mode)
{
    __shared__ float sums[NSUMS];
    const int lane = threadIdx.x & 63;
    const int wv   = threadIdx.x >> 6;   // 16 waves

    if (mode) {
        // one wave per sum slot: coalesced strided read + shuffle reduce
        for (int k = wv; k < NSUMS; k += 16) {
            float v = 0.f;
            for (int b = lane; b < NBLOCKS; b += 64) v += ws[k * PLD + b];
#pragma unroll
            for (int off = 32; off; off >>= 1) v += __shfl_down(v, off, 64);
            if (lane == 0) sums[k] = v;
        }
    } else {
        if (threadIdx.x < NSUMS) sums[threadIdx.x] = ws[threadIdx.x];
    }
    __syncthreads();

    if (threadIdx.x == 0) {
        float sum_term = 0.f, pen_last = 0.f;
        float tot_ssig = 0.f, tot_spos = 0.f;
#pragma unroll
        for (int c = 0; c < CATS; ++c) {
            float ssigc = sums[c];
            float sp    = sums[CATS + c];
            float np    = sums[2 * CATS + c];
            float nn    = rowsB - np;
            float sneg  = ssigc - sp;
            tot_ssig += ssigc;
            tot_spos += sp;
            float mp = (np > 0.f) ? sp   / fmaxf(np, 1.f) : 0.f;
            float mn = (nn > 0.f) ? sneg / fmaxf(nn, 1.f) : 0.f;
            float pen = 1.f - mp + mn;
            sum_term += pen;
            if (c == CATS - 1) pen_last = pen;
        }
        // cel = mean(sp + (1-l)*sig); sum((1-l)*sig) = sum(sig) - sum(sig*l)
        float cel = (sums[3 * CATS] + (tot_ssig - tot_spos)) * invBC;
        out[0] = cel + 0.1f * (sum_term / 15.f);
        out[1] = 0.1f * pen_last;
    }
}

extern "C" void kernel_launch(void* const* d_in, const int* in_sizes, int n_in,
                              void* d_out, int out_size, void* d_ws, size_t ws_size,
                              hipStream_t stream) {
    const float* outp = (const float*)d_in[0];
    const float* labp = (const float*)d_in[1];
    float* out = (float*)d_out;
    float* ws  = (float*)d_ws;

    const int total   = in_sizes[0];          // B * 15
    const int nFloat4 = total / 4;
    const float rowsB = (float)(total / CATS);
    const float invBC = 1.0f / (float)total;

    const size_t needed = (size_t)NSUMS * PLD * sizeof(float);
    const int mode = (ws_size >= needed) ? 1 : 0;
    if (!mode) hipMemsetAsync(ws, 0, NSUMS * sizeof(float), stream);  // only for atomic fallback

    mauch_main<<<NBLOCKS, NTHREADS, 0, stream>>>(outp, labp, ws, nFloat4, mode);
    mauch_final<<<1, 1024, 0, stream>>>(ws, out, invBC, rowsB, mode);
}